// Round 1
// baseline (195.116 us; speedup 1.0000x reference)
//
#include <hip/hip_runtime.h>
#include <math.h>

#define B 64
#define J 16
#define COL 96
#define HW (COL * COL)          // 9216
#define BJ (B * J)              // 1024
#define NT 256
#define V4_PER_THREAD (HW / 4 / NT)   // 9

// Fused kernel: one block per (b,j) slice.
// - fused weighted-MSE partial sum + argmax over the 9216-element slice
// - thread 0 gathers offset at argmax, writes x, stores per-slice partials
// - last block to finish (device-scope counter) reduces the 1024 partials
//   and writes out[0], eliminating the second dispatch.
__global__ __launch_bounds__(NT) void jm_fused_kernel(
    const float* __restrict__ offset,    // [B, 2J, HW]
    const float* __restrict__ heatmap,   // [B, J, HW]
    const float* __restrict__ target,    // [B, J, HW]
    const float* __restrict__ tw,        // [B, J, 1]
    const float* __restrict__ joints,    // [B, J, 2]
    const float* __restrict__ jvis,      // [B, J, 2]
    float* __restrict__ out,             // [1 + B*J*2]
    float* __restrict__ ws_sumsq,        // [BJ]
    float* __restrict__ ws_d2,           // [BJ]
    float* __restrict__ ws_vis,          // [BJ]
    unsigned* __restrict__ counter)      // [1], zeroed before launch
{
    const int bj  = blockIdx.x;
    const int tid = threadIdx.x;

    // Hoist the small per-slice scalars: issue these loads at t=0 so their
    // HBM latency overlaps the main loop instead of sitting in the tail.
    float w_s = 0.f, j0_s = 0.f, j1_s = 0.f, v0_s = 0.f, v1_s = 0.f;
    if (tid == 0) {
        w_s  = tw[bj];
        j0_s = joints[bj * 2];
        j1_s = joints[bj * 2 + 1];
        v0_s = jvis[bj * 2];
        v1_s = jvis[bj * 2 + 1];
    }

    const float4* p4 = (const float4*)(heatmap + (size_t)bj * HW);
    const float4* g4 = (const float4*)(target  + (size_t)bj * HW);

    float sumsq = 0.0f;
    float bestv = -3.402823466e+38f;
    int   besti = 0;

#pragma unroll
    for (int k = 0; k < V4_PER_THREAD; ++k) {
        const int i4 = k * NT + tid;          // float4 index, coalesced
        const float4 p = p4[i4];
        const float4 g = g4[i4];
        const int base = i4 * 4;
        const float d0 = p.x - g.x, d1v = p.y - g.y;
        const float d2v = p.z - g.z, d3 = p.w - g.w;
        sumsq += d0 * d0 + d1v * d1v + d2v * d2v + d3 * d3;
        // strict > keeps first occurrence (indices ascend within a thread)
        if (p.x > bestv) { bestv = p.x; besti = base;     }
        if (p.y > bestv) { bestv = p.y; besti = base + 1; }
        if (p.z > bestv) { bestv = p.z; besti = base + 2; }
        if (p.w > bestv) { bestv = p.w; besti = base + 3; }
    }

    // wave(64) reduction: sum + argmax (tie -> smaller index)
#pragma unroll
    for (int off = 32; off > 0; off >>= 1) {
        const float ov = __shfl_down(bestv, off, 64);
        const int   oi = __shfl_down(besti, off, 64);
        const float os = __shfl_down(sumsq, off, 64);
        sumsq += os;
        if (ov > bestv || (ov == bestv && oi < besti)) { bestv = ov; besti = oi; }
    }

    __shared__ float s_sum[NT / 64];
    __shared__ float s_val[NT / 64];
    __shared__ int   s_idx[NT / 64];
    __shared__ int   s_last;
    const int wave = tid >> 6;
    if ((tid & 63) == 0) { s_sum[wave] = sumsq; s_val[wave] = bestv; s_idx[wave] = besti; }
    __syncthreads();

    if (tid == 0) {
        float tot = s_sum[0];
        bestv = s_val[0]; besti = s_idx[0];
#pragma unroll
        for (int wv = 1; wv < NT / 64; ++wv) {
            tot += s_sum[wv];
            if (s_val[wv] > bestv || (s_val[wv] == bestv && s_idx[wv] < besti)) {
                bestv = s_val[wv]; besti = s_idx[wv];
            }
        }

        ws_sumsq[bj] = w_s * w_s * tot;   // diff = w*(pred-gt); square factors as w^2

        const int b = bj / J, j = bj % J;
        const int yc = besti / COL, xc = besti % COL;
        const float offx = offset[((size_t)(b * 2 * J + j))     * HW + besti];
        const float offy = offset[((size_t)(b * 2 * J + J + j)) * HW + besti];
        const float x0 = (offx + (float)xc) * (float)COL;
        const float x1 = (offy + (float)yc) * (float)COL;
        out[1 + bj * 2]     = x0;
        out[1 + bj * 2 + 1] = x1;

        const float dx = (x0 - j0_s) * v0_s * (1.0f / 256.0f);
        const float dy = (x1 - j1_s) * v1_s * (1.0f / 256.0f);
        ws_d2[bj]  = dx * dx + dy * dy;
        ws_vis[bj] = v0_s + v1_s;

        // release our partials device-wide, then take a ticket
        __threadfence();
        const unsigned t = atomicAdd(counter, 1u);
        s_last = (t == (unsigned)(gridDim.x - 1)) ? 1 : 0;
    }
    __syncthreads();

    // ---- last block: reduce the 1024 per-slice partials -> out[0] ----
    if (s_last) {
        float s1 = 0.0f, s2 = 0.0f, sv = 0.0f;
#pragma unroll
        for (int r = 0; r < BJ / NT; ++r) {
            const int i = r * NT + tid;
            // agent-scope loads: read from the coherence point (LLC), not a
            // possibly-stale per-XCD L2 line left over from the poison fill
            s1 += __hip_atomic_load(ws_sumsq + i, __ATOMIC_RELAXED, __HIP_MEMORY_SCOPE_AGENT);
            s2 += __hip_atomic_load(ws_d2    + i, __ATOMIC_RELAXED, __HIP_MEMORY_SCOPE_AGENT);
            sv += __hip_atomic_load(ws_vis   + i, __ATOMIC_RELAXED, __HIP_MEMORY_SCOPE_AGENT);
        }

#pragma unroll
        for (int off = 32; off > 0; off >>= 1) {
            s1 += __shfl_down(s1, off, 64);
            s2 += __shfl_down(s2, off, 64);
            sv += __shfl_down(sv, off, 64);
        }

        __shared__ float a1[NT / 64], a2[NT / 64], av[NT / 64];
        if ((tid & 63) == 0) { a1[wave] = s1; a2[wave] = s2; av[wave] = sv; }
        __syncthreads();

        if (tid == 0) {
            float t1 = 0.0f, t2 = 0.0f, tv = 0.0f;
#pragma unroll
            for (int i = 0; i < NT / 64; ++i) { t1 += a1[i]; t2 += a2[i]; tv += av[i]; }
            const float d1 = 0.5f * t1 / (float)(B * J * HW);
            const float n2 = tv * 0.5f;
            const float d2 = 0.5f * sqrtf(t2) / n2;
            out[0] = d1 + d2;
        }
    }
}

extern "C" void kernel_launch(void* const* d_in, const int* in_sizes, int n_in,
                              void* d_out, int out_size, void* d_ws, size_t ws_size,
                              hipStream_t stream) {
    const float* offset  = (const float*)d_in[0];
    const float* heatmap = (const float*)d_in[1];
    const float* target  = (const float*)d_in[2];
    const float* tw      = (const float*)d_in[3];
    const float* joints  = (const float*)d_in[4];
    const float* jvis    = (const float*)d_in[5];
    float* out = (float*)d_out;
    float* ws  = (float*)d_ws;   // 3 * 1024 floats + 1 counter = ~12 KB scratch
    unsigned* counter = (unsigned*)(ws + 3 * BJ);

    // workspace is re-poisoned between iterations -> counter must be zeroed
    hipMemsetAsync(counter, 0, sizeof(unsigned), stream);
    jm_fused_kernel<<<BJ, NT, 0, stream>>>(offset, heatmap, target, tw, joints, jvis,
                                           out, ws, ws + BJ, ws + 2 * BJ, counter);
}

// Round 2
// 154.167 us; speedup vs baseline: 1.2656x; 1.2656x over previous
//
#include <hip/hip_runtime.h>
#include <math.h>

#define B 64
#define J 16
#define COL 96
#define HW (COL * COL)          // 9216
#define BJ (B * J)              // 1024
#define NT 256
#define V4_PER_THREAD (HW / 4 / NT)   // 9

// Kernel 1: one block per (b,j) slice.
// - fused weighted-MSE partial sum + argmax over the 9216-element slice
// - thread 0 gathers offset at argmax, writes x, stores per-slice partials
// __launch_bounds__(256, 4): 4 waves/EU min -> VGPR cap 128. Grid is 4
// blocks/CU (1024 blocks / 256 CUs) so occupancy is grid-limited anyway;
// spending VGPRs on 18-deep load staging is free. (Round-1 lesson: at
// VGPR=32 the compiler serialized the 9 load pairs -> latency-bound.)
__global__ __launch_bounds__(NT, 4) void jm_slice_kernel(
    const float* __restrict__ offset,    // [B, 2J, HW]
    const float* __restrict__ heatmap,   // [B, J, HW]
    const float* __restrict__ target,    // [B, J, HW]
    const float* __restrict__ tw,        // [B, J, 1]
    const float* __restrict__ joints,    // [B, J, 2]
    const float* __restrict__ jvis,      // [B, J, 2]
    float* __restrict__ out,             // [1 + B*J*2]
    float* __restrict__ ws_sumsq,        // [BJ]
    float* __restrict__ ws_d2,           // [BJ]
    float* __restrict__ ws_vis)          // [BJ]
{
    const int bj  = blockIdx.x;
    const int tid = threadIdx.x;

    const float4* p4 = (const float4*)(heatmap + (size_t)bj * HW);
    const float4* g4 = (const float4*)(target  + (size_t)bj * HW);

    // Stage ALL loads first: 18 float4 loads issued back-to-back, one
    // waitcnt before compute -> 18-deep memory-level parallelism/thread.
    float4 p[V4_PER_THREAD], g[V4_PER_THREAD];
#pragma unroll
    for (int k = 0; k < V4_PER_THREAD; ++k) p[k] = p4[k * NT + tid];
#pragma unroll
    for (int k = 0; k < V4_PER_THREAD; ++k) g[k] = g4[k * NT + tid];

    float sumsq = 0.0f;
    float bestv = -3.402823466e+38f;
    int   besti = 0;

#pragma unroll
    for (int k = 0; k < V4_PER_THREAD; ++k) {
        const int base = (k * NT + tid) * 4;
        const float d0 = p[k].x - g[k].x, d1v = p[k].y - g[k].y;
        const float d2v = p[k].z - g[k].z, d3 = p[k].w - g[k].w;
        sumsq += d0 * d0 + d1v * d1v + d2v * d2v + d3 * d3;
        // strict > keeps first occurrence (indices ascend within a thread)
        if (p[k].x > bestv) { bestv = p[k].x; besti = base;     }
        if (p[k].y > bestv) { bestv = p[k].y; besti = base + 1; }
        if (p[k].z > bestv) { bestv = p[k].z; besti = base + 2; }
        if (p[k].w > bestv) { bestv = p[k].w; besti = base + 3; }
    }

    // wave(64) reduction: sum + argmax (tie -> smaller index)
#pragma unroll
    for (int off = 32; off > 0; off >>= 1) {
        const float ov = __shfl_down(bestv, off, 64);
        const int   oi = __shfl_down(besti, off, 64);
        const float os = __shfl_down(sumsq, off, 64);
        sumsq += os;
        if (ov > bestv || (ov == bestv && oi < besti)) { bestv = ov; besti = oi; }
    }

    __shared__ float s_sum[NT / 64];
    __shared__ float s_val[NT / 64];
    __shared__ int   s_idx[NT / 64];
    const int wave = tid >> 6;
    if ((tid & 63) == 0) { s_sum[wave] = sumsq; s_val[wave] = bestv; s_idx[wave] = besti; }
    __syncthreads();

    if (tid == 0) {
        float tot = s_sum[0];
        bestv = s_val[0]; besti = s_idx[0];
#pragma unroll
        for (int wv = 1; wv < NT / 64; ++wv) {
            tot += s_sum[wv];
            if (s_val[wv] > bestv || (s_val[wv] == bestv && s_idx[wv] < besti)) {
                bestv = s_val[wv]; besti = s_idx[wv];
            }
        }

        const float w = tw[bj];
        ws_sumsq[bj] = w * w * tot;   // diff = w*(pred-gt); square factors as w^2

        const int b = bj / J, j = bj % J;
        const int yc = besti / COL, xc = besti % COL;
        const float offx = offset[((size_t)(b * 2 * J + j))     * HW + besti];
        const float offy = offset[((size_t)(b * 2 * J + J + j)) * HW + besti];
        const float x0 = (offx + (float)xc) * (float)COL;
        const float x1 = (offy + (float)yc) * (float)COL;
        out[1 + bj * 2]     = x0;
        out[1 + bj * 2 + 1] = x1;

        const float v0 = jvis[bj * 2], v1 = jvis[bj * 2 + 1];
        const float dx = (x0 - joints[bj * 2])     * v0 * (1.0f / 256.0f);
        const float dy = (x1 - joints[bj * 2 + 1]) * v1 * (1.0f / 256.0f);
        ws_d2[bj]  = dx * dx + dy * dy;
        ws_vis[bj] = v0 + v1;
    }
}

// Kernel 2: single block reduces the 1024 per-slice partials -> out[0]
__global__ __launch_bounds__(1024) void jm_final_kernel(
    const float* __restrict__ ws_sumsq,
    const float* __restrict__ ws_d2,
    const float* __restrict__ ws_vis,
    float* __restrict__ out)
{
    const int tid = threadIdx.x;
    float s1 = ws_sumsq[tid];
    float s2 = ws_d2[tid];
    float sv = ws_vis[tid];

#pragma unroll
    for (int off = 32; off > 0; off >>= 1) {
        s1 += __shfl_down(s1, off, 64);
        s2 += __shfl_down(s2, off, 64);
        sv += __shfl_down(sv, off, 64);
    }

    __shared__ float a1[16], a2[16], av[16];
    const int wave = tid >> 6;
    if ((tid & 63) == 0) { a1[wave] = s1; a2[wave] = s2; av[wave] = sv; }
    __syncthreads();

    if (tid == 0) {
        float t1 = 0.0f, t2 = 0.0f, tv = 0.0f;
#pragma unroll
        for (int i = 0; i < 16; ++i) { t1 += a1[i]; t2 += a2[i]; tv += av[i]; }
        const float d1 = 0.5f * t1 / (float)(B * J * HW);
        const float n2 = tv * 0.5f;
        const float d2 = 0.5f * sqrtf(t2) / n2;
        out[0] = d1 + d2;
    }
}

extern "C" void kernel_launch(void* const* d_in, const int* in_sizes, int n_in,
                              void* d_out, int out_size, void* d_ws, size_t ws_size,
                              hipStream_t stream) {
    const float* offset  = (const float*)d_in[0];
    const float* heatmap = (const float*)d_in[1];
    const float* target  = (const float*)d_in[2];
    const float* tw      = (const float*)d_in[3];
    const float* joints  = (const float*)d_in[4];
    const float* jvis    = (const float*)d_in[5];
    float* out = (float*)d_out;
    float* ws  = (float*)d_ws;   // 3 * 1024 floats = 12 KB scratch

    jm_slice_kernel<<<BJ, NT, 0, stream>>>(offset, heatmap, target, tw, joints, jvis,
                                           out, ws, ws + BJ, ws + 2 * BJ);
    jm_final_kernel<<<1, 1024, 0, stream>>>(ws, ws + BJ, ws + 2 * BJ, out);
}